// Round 11
// baseline (231.675 us; speedup 1.0000x reference)
//
#include <hip/hip_runtime.h>
#include <hip/hip_bf16.h>

// Problem constants (B=4, Tq=Tk=512, Q=K=1024, C=256)
#define M_ROWS 2048   // B*Tq = B*Tk
#define KDIM   1024
#define CDIM   256
#define TQ     512
#define TK     512

#define GBM 64        // m rows per gemm block: 4 waves x 16
#define GBN 32        // c cols per gemm block
#define CK  128       // k chunk per barrier-pair
#define NBLOCKS 1024u

// 2*log2(e): tanh(x) = 1 - 2/(exp2(2log2e * x) + 1)
#define SCALE2LOG2E 2.8853900817779268f

typedef __attribute__((ext_vector_type(8))) short short8;
typedef __attribute__((ext_vector_type(8))) unsigned short ushort8;
typedef __attribute__((ext_vector_type(4))) float floatx4;
typedef __attribute__((ext_vector_type(2))) float f32x2;

__device__ __forceinline__ short2 cvt2(float x, float y) {
    __hip_bfloat162 h = __float22bfloat162_rn(make_float2(x, y));
    short2 r;
    __builtin_memcpy(&r, &h, sizeof(r));
    return r;
}
__device__ __forceinline__ unsigned short f2bf1(float x) {
    return (unsigned short)cvt2(x, x).x;
}
__device__ __forceinline__ float bf2f(unsigned short u) {
    return __builtin_bit_cast(float, (unsigned)u << 16);
}
__device__ __forceinline__ f32x2 splat2(float x) { return (f32x2){x, x}; }

union SharedU {
    short ws[GBN][CK + 8];                               // gemm: 8704 B
    struct { float qs[64][36]; float ks[64][36]; } bah;  // bah: 18432 B
};

// Fused: phase 1 (blocks 0..511) = R9 MFMA GEMM -> E bf16; manual grid
// barrier (all 1024 blocks co-resident by construction: LDS ~19.5KB -> 8/CU
// cap, launch_bounds(256,4) -> <=128 VGPR -> >=4/CU, 4*256 = 1024);
// phase 2 (all 1024 blocks) = R6 bahdanau.
__global__ __launch_bounds__(256, 4) void fused_kernel(
    const float* __restrict__ Aq, const float* __restrict__ Ak,
    const float* __restrict__ Wq, const float* __restrict__ Wk,
    const float* __restrict__ w_attn, const float* __restrict__ b_attn,
    unsigned short* __restrict__ Eqs, unsigned short* __restrict__ Ek,
    unsigned* __restrict__ counter, float* __restrict__ out)
{
    __shared__ SharedU sh;
    __shared__ __align__(16) float sl[CDIM];
    __shared__ float partial[4];

    const int id = blockIdx.x;
    const int t  = threadIdx.x;

    if (id < 512) {
        // ================= phase 1: GEMM (R9 body) =================
        const int z  = id >> 8;
        const int by = (id >> 5) & 7;
        const int bx = id & 31;
        const float* A = z ? Ak : Aq;
        const float* W = z ? Wk : Wq;
        unsigned short* E = z ? Ek : Eqs;

        const int lane = t & 63;
        const int wave = t >> 6;
        const int m0   = bx * GBM;
        const int n0   = by * GBN;
        const int li   = lane & 15;
        const int qd   = lane >> 4;

        const int row = m0 + wave * 16 + li;
        const float* Arow = A + (size_t)row * KDIM + qd * 8;

        const int kr = t >> 1;          // 0..127
        const int h  = t & 1;
        const float* Wst = W + (size_t)kr * CDIM + n0 + h * 16;

        floatx4 acc0 = {0.f, 0.f, 0.f, 0.f};
        floatx4 acc1 = {0.f, 0.f, 0.f, 0.f};

        float4 wreg[4];
        #pragma unroll
        for (int u = 0; u < 4; ++u) wreg[u] = *(const float4*)&Wst[4 * u];

        for (int ck = 0; ck < KDIM / CK; ++ck) {
            __syncthreads();                         // prev chunk frag reads done
            #pragma unroll
            for (int u = 0; u < 4; ++u) {
                short2 e0 = cvt2(wreg[u].x, wreg[u].y);
                short2 e1 = cvt2(wreg[u].z, wreg[u].w);
                const int c = h * 16 + 4 * u;
                sh.ws[c + 0][kr] = e0.x;
                sh.ws[c + 1][kr] = e0.y;
                sh.ws[c + 2][kr] = e1.x;
                sh.ws[c + 3][kr] = e1.y;
            }
            __syncthreads();                         // Ws ready
            if (ck + 1 < KDIM / CK) {
                const float* Wn = Wst + (size_t)(ck + 1) * CK * CDIM;
                #pragma unroll
                for (int u = 0; u < 4; ++u) wreg[u] = *(const float4*)&Wn[4 * u];
            }
            #pragma unroll
            for (int s = 0; s < 4; ++s) {
                const int kk = ck * CK + s * 32;
                float4 a0 = *(const float4*)&Arow[kk];
                float4 a1 = *(const float4*)&Arow[kk + 4];
                short8 af0 = *(const short8*)&sh.ws[li][s * 32 + qd * 8];
                short8 af1 = *(const short8*)&sh.ws[16 + li][s * 32 + qd * 8];
                short2 p0 = cvt2(a0.x, a0.y), p1 = cvt2(a0.z, a0.w);
                short2 p2 = cvt2(a1.x, a1.y), p3 = cvt2(a1.z, a1.w);
                short8 bv = { p0.x, p0.y, p1.x, p1.y, p2.x, p2.y, p3.x, p3.y };
                acc0 = __builtin_amdgcn_mfma_f32_16x16x32_bf16(af0, bv, acc0, 0, 0, 0);
                acc1 = __builtin_amdgcn_mfma_f32_16x16x32_bf16(af1, bv, acc1, 0, 0, 0);
            }
        }

        #pragma unroll
        for (int r = 0; r < 4; ++r) {
            const int c0 = n0 + qd * 4 + r;
            const int c1 = c0 + 16;
            float s0 = z ? 1.0f : (-0.5f / w_attn[c0]);
            float s1 = z ? 1.0f : (-0.5f / w_attn[c1]);
            float v0 = __builtin_amdgcn_exp2f(acc0[r] * SCALE2LOG2E) * s0;
            float v1 = __builtin_amdgcn_exp2f(acc1[r] * SCALE2LOG2E) * s1;
            E[(size_t)c0 * M_ROWS + row] = f2bf1(v0);
            E[(size_t)c1 * M_ROWS + row] = f2bf1(v1);
        }
    }

    // ================= grid barrier =================
    __syncthreads();                 // drains vmcnt -> this block's stores in L2
    if (t == 0) {
        __threadfence();             // wbL2: publish this XCD's E lines
        atomicAdd(counter, 1u);      // device-scope (m20)
        while (atomicAdd(counter, 0u) < NBLOCKS) __builtin_amdgcn_s_sleep(2);
        __threadfence();             // inv: discard stale L1/L2 before E reads
    }
    __syncthreads();

    // ================= phase 2: bahdanau (R6 body) =================
    const int qb = id & 15;
    const int kb = (id >> 4) & 15;
    const int b  = id >> 8;
    const int q0 = qb * 32;
    const int k0 = kb * 32;
    const int gq = b * TQ + q0;
    const int gk = b * TK + k0;
    const int tq = (t >> 4) * 2;      // q base (broadcast LDS reads)
    const int tk = (t & 15) * 2;      // k base (lanes -> consecutive k)

    const int lr = t >> 2;            // stage c-row 0..63
    const int lc = (t & 3) * 8;       // stage col*8

    {   // prologue: s_c and sum(w); CDIM == blockDim.x == 256
        float wv = w_attn[t];
        sl[t] = -0.5f / wv;
        float sum = wv;
        #pragma unroll
        for (int o = 32; o >= 1; o >>= 1) sum += __shfl_down(sum, o);
        if ((t & 63) == 0) partial[t >> 6] = sum;
    }

    ushort8 qu = *(const ushort8*)&Eqs[(size_t)lr * M_ROWS + gq + lc];
    ushort8 ku = *(const ushort8*)&Ek [(size_t)lr * M_ROWS + gk + lc];

    f32x2 accA = {0.f, 0.f};
    f32x2 accB = {0.f, 0.f};

    for (int ch = 0; ch < 4; ++ch) {
        __syncthreads();
        *(float4*)&sh.bah.qs[lr][lc]     = make_float4(bf2f(qu[0]), bf2f(qu[1]), bf2f(qu[2]), bf2f(qu[3]));
        *(float4*)&sh.bah.qs[lr][lc + 4] = make_float4(bf2f(qu[4]), bf2f(qu[5]), bf2f(qu[6]), bf2f(qu[7]));
        *(float4*)&sh.bah.ks[lr][lc]     = make_float4(bf2f(ku[0]), bf2f(ku[1]), bf2f(ku[2]), bf2f(ku[3]));
        *(float4*)&sh.bah.ks[lr][lc + 4] = make_float4(bf2f(ku[4]), bf2f(ku[5]), bf2f(ku[6]), bf2f(ku[7]));
        __syncthreads();
        if (ch < 3) {
            const int c1 = (ch + 1) * 64;
            qu = *(const ushort8*)&Eqs[(size_t)(c1 + lr) * M_ROWS + gq + lc];
            ku = *(const ushort8*)&Ek [(size_t)(c1 + lr) * M_ROWS + gk + lc];
        }
        const int cb = ch * 64;
        #pragma unroll
        for (int cc = 0; cc < 64; cc += 4) {
            float4 s4 = *(const float4*)&sl[cb + cc];
            f32x2 q1 = *(const f32x2*)&sh.bah.qs[cc + 0][tq];
            f32x2 q2 = *(const f32x2*)&sh.bah.qs[cc + 1][tq];
            f32x2 q3 = *(const f32x2*)&sh.bah.qs[cc + 2][tq];
            f32x2 q4 = *(const f32x2*)&sh.bah.qs[cc + 3][tq];
            f32x2 k1 = *(const f32x2*)&sh.bah.ks[cc + 0][tk];
            f32x2 k2 = *(const f32x2*)&sh.bah.ks[cc + 1][tk];
            f32x2 k3 = *(const f32x2*)&sh.bah.ks[cc + 2][tk];
            f32x2 k4 = *(const f32x2*)&sh.bah.ks[cc + 3][tk];
            {   // group A: q component .x
                f32x2 f1 = __builtin_elementwise_fma(splat2(q1.x), k1, splat2(s4.x));
                f32x2 f2 = __builtin_elementwise_fma(splat2(q2.x), k2, splat2(s4.y));
                f32x2 f3 = __builtin_elementwise_fma(splat2(q3.x), k3, splat2(s4.z));
                f32x2 f4 = __builtin_elementwise_fma(splat2(q4.x), k4, splat2(s4.w));
                f32x2 p12 = f1 * f2, p34 = f3 * f4;
                f32x2 s12 = f1 + f2, s34 = f3 + f4;
                f32x2 num = __builtin_elementwise_fma(s12, p34, s34 * p12);
                f32x2 den = p12 * p34;
                f32x2 r = {__builtin_amdgcn_rcpf(den.x), __builtin_amdgcn_rcpf(den.y)};
                accA = __builtin_elementwise_fma(num, r, accA);
            }
            {   // group B: q component .y
                f32x2 f1 = __builtin_elementwise_fma(splat2(q1.y), k1, splat2(s4.x));
                f32x2 f2 = __builtin_elementwise_fma(splat2(q2.y), k2, splat2(s4.y));
                f32x2 f3 = __builtin_elementwise_fma(splat2(q3.y), k3, splat2(s4.z));
                f32x2 f4 = __builtin_elementwise_fma(splat2(q4.y), k4, splat2(s4.w));
                f32x2 p12 = f1 * f2, p34 = f3 * f4;
                f32x2 s12 = f1 + f2, s34 = f3 + f4;
                f32x2 num = __builtin_elementwise_fma(s12, p34, s34 * p12);
                f32x2 den = p12 * p34;
                f32x2 r = {__builtin_amdgcn_rcpf(den.x), __builtin_amdgcn_rcpf(den.y)};
                accB = __builtin_elementwise_fma(num, r, accB);
            }
        }
    }

    const float bias2 = *b_attn + partial[0] + partial[1] + partial[2] + partial[3];
    float* o = out + ((size_t)b * TQ + q0 + tq) * TK + k0 + tk;
    *(float2*)&o[0]  = make_float2(accA.x + bias2, accA.y + bias2);
    *(float2*)&o[TK] = make_float2(accB.x + bias2, accB.y + bias2);
}

extern "C" void kernel_launch(void* const* d_in, const int* in_sizes, int n_in,
                              void* d_out, int out_size, void* d_ws, size_t ws_size,
                              hipStream_t stream) {
    const float* query  = (const float*)d_in[0];
    const float* key    = (const float*)d_in[1];
    const float* Wq     = (const float*)d_in[2];
    const float* Wk     = (const float*)d_in[3];
    const float* w_attn = (const float*)d_in[4];
    const float* b_attn = (const float*)d_in[5];
    float* out = (float*)d_out;

    unsigned short* Eqs = (unsigned short*)d_ws;        // 256x2048 bf16 = 1 MB
    unsigned short* Ek  = Eqs + (size_t)CDIM * M_ROWS;  // 1 MB
    unsigned* counter = (unsigned*)((char*)d_ws + (2u << 20));

    hipMemsetAsync(counter, 0, sizeof(unsigned), stream);
    fused_kernel<<<dim3(NBLOCKS), dim3(256), 0, stream>>>(
        query, key, Wq, Wk, w_attn, b_attn, Eqs, Ek, counter, out);
}

// Round 12
// 111.384 us; speedup vs baseline: 2.0800x; 2.0800x over previous
//
#include <hip/hip_runtime.h>
#include <hip/hip_bf16.h>

// Problem constants (B=4, Tq=Tk=512, Q=K=1024, C=256)
#define M_ROWS 2048   // B*Tq = B*Tk
#define KDIM   1024
#define CDIM   256
#define TQ     512
#define TK     512

#define GBM 64        // m rows per block (gemm): 4 waves x 16
#define GBN 32        // c cols per block (gemm)
#define GBK 32        // k per iter

// 2*log2(e): tanh(x) = 1 - 2/(exp2(2log2e * x) + 1)
#define SCALE2LOG2E 2.8853900817779268f

typedef __attribute__((ext_vector_type(8))) short short8;
typedef __attribute__((ext_vector_type(8))) unsigned short ushort8;
typedef __attribute__((ext_vector_type(4))) float floatx4;
typedef __attribute__((ext_vector_type(2))) float f32x2;

__device__ __forceinline__ short2 cvt2(float x, float y) {
    __hip_bfloat162 h = __float22bfloat162_rn(make_float2(x, y));
    short2 r;
    __builtin_memcpy(&r, &h, sizeof(r));
    return r;
}
__device__ __forceinline__ unsigned short f2bf1(float x) {
    return (unsigned short)cvt2(x, x).x;
}
__device__ __forceinline__ float bf2f(unsigned short u) {
    return __builtin_bit_cast(float, (unsigned)u << 16);
}
__device__ __forceinline__ f32x2 splat2(float x) { return (f32x2){x, x}; }

// MFMA GEMM producing E_bf16[c][m] = bf16(exp2(S * sum_k A[m][k]*W[k][c])),
// q-side prescaled by s_c = -0.5/w_c.  (R7 structure — best measured total.)
// A-fragment (MFMA B-operand) loaded directly from global per lane; W staged
// in LDS; depth-2 register prefetch on both.
__global__ __launch_bounds__(256) void gemm_mfma_kernel(
    const float* __restrict__ Aq, const float* __restrict__ Ak,
    const float* __restrict__ Wq, const float* __restrict__ Wk,
    const float* __restrict__ w_attn,
    unsigned short* __restrict__ Eq, unsigned short* __restrict__ Ek)
{
    __shared__ short Ws[GBN][GBK + 8];   // [c][k] 32x40 shorts (80B rows)

    const int z = blockIdx.z;
    const float* A = z ? Ak : Aq;
    const float* W = z ? Wk : Wq;
    unsigned short* E = z ? Ek : Eq;

    const int t    = threadIdx.x;
    const int lane = t & 63;
    const int wave = t >> 6;
    const int m0   = blockIdx.x * GBM;
    const int n0   = blockIdx.y * GBN;

    const int wr = t >> 3;            // W stage: k row 0..31
    const int wc = (t & 7) * 4;       // W stage: c col 0,4,..,28
    const int li = lane & 15;
    const int qd = lane >> 4;

    const int row = m0 + wave * 16 + li;        // this lane's m row
    const float* Arow = A + (size_t)row * KDIM + qd * 8;

    floatx4 acc0 = {0.f, 0.f, 0.f, 0.f};   // c = n0 + qd*4 + r
    floatx4 acc1 = {0.f, 0.f, 0.f, 0.f};   // c + 16

    // depth-2 prefetch
    float4 pa0[2], pa1[2], pw[2];
    pa0[0] = *(const float4*)&Arow[0];
    pa1[0] = *(const float4*)&Arow[4];
    pw[0]  = *(const float4*)&W[(size_t)wr * CDIM + n0 + wc];
    pa0[1] = *(const float4*)&Arow[GBK];
    pa1[1] = *(const float4*)&Arow[GBK + 4];
    pw[1]  = *(const float4*)&W[(size_t)(GBK + wr) * CDIM + n0 + wc];

    for (int it = 0; it < KDIM / GBK; ++it) {
        const int s = it & 1;
        __syncthreads();                       // prev-iter Ws reads done
        short2 u0 = cvt2(pw[s].x, pw[s].y), u1 = cvt2(pw[s].z, pw[s].w);
        Ws[wc + 0][wr] = u0.x;
        Ws[wc + 1][wr] = u0.y;
        Ws[wc + 2][wr] = u1.x;
        Ws[wc + 3][wr] = u1.y;
        short2 p0 = cvt2(pa0[s].x, pa0[s].y), p1 = cvt2(pa0[s].z, pa0[s].w);
        short2 p2 = cvt2(pa1[s].x, pa1[s].y), p3 = cvt2(pa1[s].z, pa1[s].w);
        short8 bv = { p0.x, p0.y, p1.x, p1.y, p2.x, p2.y, p3.x, p3.y };
        __syncthreads();                       // Ws ready
        if (it + 2 < KDIM / GBK) {             // refill slot s (just consumed)
            const int k0 = (it + 2) * GBK;
            pa0[s] = *(const float4*)&Arow[k0];
            pa1[s] = *(const float4*)&Arow[k0 + 4];
            pw[s]  = *(const float4*)&W[(size_t)(k0 + wr) * CDIM + n0 + wc];
        }
        short8 af0 = *(const short8*)&Ws[li][qd * 8];
        short8 af1 = *(const short8*)&Ws[16 + li][qd * 8];
        acc0 = __builtin_amdgcn_mfma_f32_16x16x32_bf16(af0, bv, acc0, 0, 0, 0);
        acc1 = __builtin_amdgcn_mfma_f32_16x16x32_bf16(af1, bv, acc1, 0, 0, 0);
    }

    #pragma unroll
    for (int r = 0; r < 4; ++r) {
        const int c0 = n0 + qd * 4 + r;
        const int c1 = c0 + 16;
        float s0 = z ? 1.0f : (-0.5f / w_attn[c0]);
        float s1 = z ? 1.0f : (-0.5f / w_attn[c1]);
        float v0 = __builtin_amdgcn_exp2f(acc0[r] * SCALE2LOG2E) * s0;
        float v1 = __builtin_amdgcn_exp2f(acc1[r] * SCALE2LOG2E) * s1;
        E[(size_t)c0 * M_ROWS + row] = f2bf1(v0);
        E[(size_t)c1 * M_ROWS + row] = f2bf1(v1);
    }
}

// scores[b][q][k] = (b_attn + sum_c w_c) + sum_c rcp(f_c),
//   f_c = fma(Eqs[c][q], Ek[c][k], s_c),  Eqs = s_c*e^{2 q2ctx}, Ek = e^{2 k2ctx}
// 4-way pairing: 1/f1+1/f2+1/f3+1/f4 = ((f1+f2)f3f4+(f3+f4)f1f2)*rcp(f1f2f3f4).
// E is bf16 in global (halved fetch), converted to fp32 during LDS staging.
__global__ __launch_bounds__(256) void bahdanau_kernel(
    const unsigned short* __restrict__ Eqs, const unsigned short* __restrict__ Ek,
    const float* __restrict__ w_attn, const float* __restrict__ b_attn,
    float* __restrict__ out)
{
    __shared__ float qs[64][36];          // [c][q] stride 36
    __shared__ float ks[64][36];          // [c][k]
    __shared__ __align__(16) float sl[CDIM];  // s_c = -0.5/w_c
    __shared__ float partial[4];          // per-wave w sums

    const int t  = threadIdx.x;
    const int b  = blockIdx.z;
    const int q0 = blockIdx.x * 32;
    const int k0 = blockIdx.y * 32;
    const int gq = b * TQ + q0;
    const int gk = b * TK + k0;
    const int tq = (t >> 4) * 2;      // q base (broadcast LDS reads)
    const int tk = (t & 15) * 2;      // k base (lanes -> consecutive k)

    const int lr = t >> 2;            // stage c-row 0..63
    const int lc = (t & 3) * 8;       // stage col*8

    {   // prologue: s_c and sum(w); CDIM == blockDim.x == 256
        float wv = w_attn[t];
        sl[t] = -0.5f / wv;
        float sum = wv;
        #pragma unroll
        for (int o = 32; o >= 1; o >>= 1) sum += __shfl_down(sum, o);
        if ((t & 63) == 0) partial[t >> 6] = sum;
    }

    // prefetch chunk 0 (16B = 8 bf16 per side per thread)
    ushort8 qu = *(const ushort8*)&Eqs[(size_t)lr * M_ROWS + gq + lc];
    ushort8 ku = *(const ushort8*)&Ek [(size_t)lr * M_ROWS + gk + lc];

    f32x2 accA = {0.f, 0.f};          // q row tq,   k pair
    f32x2 accB = {0.f, 0.f};          // q row tq+1, k pair

    for (int ch = 0; ch < 4; ++ch) {
        __syncthreads();              // previous chunk's compute done
        *(float4*)&qs[lr][lc]     = make_float4(bf2f(qu[0]), bf2f(qu[1]), bf2f(qu[2]), bf2f(qu[3]));
        *(float4*)&qs[lr][lc + 4] = make_float4(bf2f(qu[4]), bf2f(qu[5]), bf2f(qu[6]), bf2f(qu[7]));
        *(float4*)&ks[lr][lc]     = make_float4(bf2f(ku[0]), bf2f(ku[1]), bf2f(ku[2]), bf2f(ku[3]));
        *(float4*)&ks[lr][lc + 4] = make_float4(bf2f(ku[4]), bf2f(ku[5]), bf2f(ku[6]), bf2f(ku[7]));
        __syncthreads();
        if (ch < 3) {                 // prefetch next chunk
            const int c1 = (ch + 1) * 64;
            qu = *(const ushort8*)&Eqs[(size_t)(c1 + lr) * M_ROWS + gq + lc];
            ku = *(const ushort8*)&Ek [(size_t)(c1 + lr) * M_ROWS + gk + lc];
        }
        const int cb = ch * 64;
        #pragma unroll
        for (int cc = 0; cc < 64; cc += 4) {
            float4 s4 = *(const float4*)&sl[cb + cc];
            f32x2 q1 = *(const f32x2*)&qs[cc + 0][tq];
            f32x2 q2 = *(const f32x2*)&qs[cc + 1][tq];
            f32x2 q3 = *(const f32x2*)&qs[cc + 2][tq];
            f32x2 q4 = *(const f32x2*)&qs[cc + 3][tq];
            f32x2 k1 = *(const f32x2*)&ks[cc + 0][tk];
            f32x2 k2 = *(const f32x2*)&ks[cc + 1][tk];
            f32x2 k3 = *(const f32x2*)&ks[cc + 2][tk];
            f32x2 k4 = *(const f32x2*)&ks[cc + 3][tk];
            {   // group A: q component .x
                f32x2 f1 = __builtin_elementwise_fma(splat2(q1.x), k1, splat2(s4.x));
                f32x2 f2 = __builtin_elementwise_fma(splat2(q2.x), k2, splat2(s4.y));
                f32x2 f3 = __builtin_elementwise_fma(splat2(q3.x), k3, splat2(s4.z));
                f32x2 f4 = __builtin_elementwise_fma(splat2(q4.x), k4, splat2(s4.w));
                f32x2 p12 = f1 * f2, p34 = f3 * f4;
                f32x2 s12 = f1 + f2, s34 = f3 + f4;
                f32x2 num = __builtin_elementwise_fma(s12, p34, s34 * p12);
                f32x2 den = p12 * p34;
                f32x2 r = {__builtin_amdgcn_rcpf(den.x), __builtin_amdgcn_rcpf(den.y)};
                accA = __builtin_elementwise_fma(num, r, accA);
            }
            {   // group B: q component .y
                f32x2 f1 = __builtin_elementwise_fma(splat2(q1.y), k1, splat2(s4.x));
                f32x2 f2 = __builtin_elementwise_fma(splat2(q2.y), k2, splat2(s4.y));
                f32x2 f3 = __builtin_elementwise_fma(splat2(q3.y), k3, splat2(s4.z));
                f32x2 f4 = __builtin_elementwise_fma(splat2(q4.y), k4, splat2(s4.w));
                f32x2 p12 = f1 * f2, p34 = f3 * f4;
                f32x2 s12 = f1 + f2, s34 = f3 + f4;
                f32x2 num = __builtin_elementwise_fma(s12, p34, s34 * p12);
                f32x2 den = p12 * p34;
                f32x2 r = {__builtin_amdgcn_rcpf(den.x), __builtin_amdgcn_rcpf(den.y)};
                accB = __builtin_elementwise_fma(num, r, accB);
            }
        }
    }

    const float bias2 = *b_attn + partial[0] + partial[1] + partial[2] + partial[3];
    float* o = out + ((size_t)b * TQ + q0 + tq) * TK + k0 + tk;
    *(float2*)&o[0]  = make_float2(accA.x + bias2, accA.y + bias2);
    *(float2*)&o[TK] = make_float2(accB.x + bias2, accB.y + bias2);
}

extern "C" void kernel_launch(void* const* d_in, const int* in_sizes, int n_in,
                              void* d_out, int out_size, void* d_ws, size_t ws_size,
                              hipStream_t stream) {
    const float* query  = (const float*)d_in[0];
    const float* key    = (const float*)d_in[1];
    const float* Wq     = (const float*)d_in[2];
    const float* Wk     = (const float*)d_in[3];
    const float* w_attn = (const float*)d_in[4];
    const float* b_attn = (const float*)d_in[5];
    float* out = (float*)d_out;

    unsigned short* Eqs = (unsigned short*)d_ws;        // 256x2048 bf16 = 1 MB
    unsigned short* Ek  = Eqs + (size_t)CDIM * M_ROWS;  // 1 MB

    dim3 gemm_grid(M_ROWS / GBM, CDIM / GBN, 2);   // 32 x 8 x 2 = 512 blocks
    gemm_mfma_kernel<<<gemm_grid, 256, 0, stream>>>(query, key, Wq, Wk, w_attn, Eqs, Ek);

    dim3 main_grid(TQ / 32, TK / 32, 4);           // 16 x 16 x 4 = 1024 blocks
    bahdanau_kernel<<<main_grid, 256, 0, stream>>>(Eqs, Ek, w_attn, b_attn, out);
}